// Round 1
// 1112.216 us; speedup vs baseline: 1.0217x; 1.0217x over previous
//
#include <hip/hip_runtime.h>

#define LOG2PI 1.837877f
#define LN2 0.6931471805599453f
#define RLN2 1.4426950408889634f
#define NLAB 46
#define NPAD 48           // children padded to 48 with poisoned carry rows
#define KK 4
#define LSEQ 512
#define KC 184            // KK*NLAB
#define BLOCK 832         // 13 waves: 12 A-waves + light emission wave 12
#define NA 736            // 46 parents * 16 lanes
#define EMB 768           // emission wave start
#define PADZ -1e37f       // pad-row z: finite, below every real key, no NaN on pack

typedef float v2f __attribute__((ext_vector_type(2)));

__device__ __forceinline__ float fastrcp(float x){ return __builtin_amdgcn_rcpf(x); }
__device__ __forceinline__ float flog2(float x){ return __builtin_amdgcn_logf(x); }
__device__ __forceinline__ float fmed3(float a, float b, float c){
    return __builtin_amdgcn_fmed3f(a, b, c);
}
template<int CTRL>
__device__ __forceinline__ float dppq(float v){   // DPP exchange (VALU pipe)
    return __uint_as_float((unsigned)__builtin_amdgcn_mov_dpp(
        (int)__float_as_uint(v), CTRL, 0xF, 0xF, false));
}
template<int OFF>
__device__ __forceinline__ float swz(float v){    // ds_swizzle xor (LDS pipe)
    return __uint_as_float((unsigned)__builtin_amdgcn_ds_swizzle(
        (int)__float_as_uint(v), OFF));
}
template<int N> struct IC { static constexpr int value = N; };

__global__ __launch_bounds__(BLOCK, 4) void lveg_kernel(
    const int* __restrict__ tokens,
    const float* __restrict__ s_w_tab,
    const float* __restrict__ s_m_tab,
    const float* __restrict__ s_v_tab,
    const float* __restrict__ t_weight,
    const float* __restrict__ t_mu,
    const float* __restrict__ t_var_p,
    float* __restrict__ out)
{
    // carry per child c (row = 48B = 3 float4), dword layout:
    // [lam0,lam1, glam0,glam1, z0,z1, lam2,lam3, glam2,glam3, z2,z3]
    // (z entries stored scaled by RLN2 for the selection key path)
    __shared__ float4 pkc4[2][NPAD][3];
    __shared__ float  scv[KC];           // raw carry scores (final logsumexp)
    __shared__ float4 emi[2][NLAB];      // emission: sw, 1/sv, sm/sv, z2
    __shared__ int    tokL[LSEQ];
    __shared__ float4 tabA[NLAB*NLAB];   // per-(c,p): e0, e1, invDetS, l11
    __shared__ float2 tabB[NLAB*NLAB];   // per-(c,p): l01, A(=zeta1+LOG2PI+tw)

    const int b = blockIdx.x;
    const int tid = threadIdx.x;
    const int s = tid & 15;              // lane within 16-lane parent group
    const int p = tid >> 4;              // parent label 0..51
    const bool isA = (p < NLAB);
    const float NEGINF = __uint_as_float(0xFF800000u);

    // ---- one-time: phase-C constant tables into LDS + token preload ----
    for (int cp = tid; cp < NLAB*NLAB; cp += BLOCK) {
        float v0 = t_var_p[cp*3+0], v1 = t_var_p[cp*3+1], v2 = t_var_p[cp*3+2];
        float tm0 = t_mu[cp*2+0],  tm1 = t_mu[cp*2+1];
        float S00 = v0*v0 + v1*v1, S01 = v1*v2, S11 = v2*v2;
        float det = S00*S11 - S01*S01;
        float inv = 1.0f / det;
        float l00 = S11*inv, l01 = -S01*inv, l11 = S00*inv;
        float e0 = l00*tm0 + l01*tm1;
        float e1 = l01*tm0 + l11*tm1;
        float q1 = e0*(S00*e0 + S01*e1) + e1*(S01*e0 + S11*e1);
        float zeta1 = -0.5f*(2.0f*LOG2PI + __logf(det) + q1);
        tabA[cp] = make_float4(e0, e1, inv, l11);
        tabB[cp] = make_float2(l01, zeta1 + LOG2PI + t_weight[cp]);
    }
    for (int i = tid; i < LSEQ; i += BLOCK) tokL[i] = tokens[b*LSEQ + i];

    // ---- one-time: phase-A per-(c,p) constants in registers ----
    float rce0[3], rl11[3], rinv[3], rl11s[3], rqbs[3], rqes[3], rqcs[3], rAs[3];
    if (isA) {
#pragma unroll
        for (int ci = 0; ci < 3; ++ci) {
            int c = s + 16*ci;
            if (c < NLAB) {
                int cp = c*NLAB + p;
                float v0 = t_var_p[cp*3+0], v1 = t_var_p[cp*3+1], v2 = t_var_p[cp*3+2];
                float tm0 = t_mu[cp*2+0],  tm1 = t_mu[cp*2+1];
                float S00 = v0*v0 + v1*v1, S01 = v1*v2, S11 = v2*v2;
                float det = S00*S11 - S01*S01;
                float inv = 1.0f / det;
                float l00 = S11*inv, l01 = -S01*inv, l11 = S00*inv;
                float e0 = l00*tm0 + l01*tm1;
                float e1 = l01*tm0 + l11*tm1;
                float q1 = e0*(S00*e0 + S01*e1) + e1*(S01*e0 + S11*e1);
                float zeta1 = -0.5f*(2.0f*LOG2PI + __logf(det) + q1);
                rce0[ci]  = e0;
                rl11[ci]  = l11;
                rinv[ci]  = inv;
                rl11s[ci] = l11 * RLN2;
                rqbs[ci]  = 2.0f*l01*e1 * RLN2;
                rqes[ci]  = e1*e1 * RLN2;
                rqcs[ci]  = l00*e1*e1 * RLN2;
                rAs[ci]   = (zeta1 + LOG2PI + t_weight[cp]) * RLN2;
            } else {
                // pad children 46,47: finite math, key dominated by z=PADZ
                rce0[ci]=0.f; rl11[ci]=0.f; rinv[ci]=1.f; rl11s[ci]=0.f;
                rqbs[ci]=0.f; rqes[ci]=0.f; rqcs[ci]=0.f; rAs[ci]=0.f;
            }
        }
    }

    // ---- carry init from emission at position 0 ----
    if (tid < NLAB) {
        int tok0 = tokens[b * LSEQ];
        float sw  = s_w_tab[tok0*NLAB + tid];
        float sm  = s_m_tab[tok0*NLAB + tid];
        float svr = s_v_tab[tok0*NLAB + tid];
        float gv = svr*svr;
        float lam2 = 1.0f / gv;
        float glam = sm * lam2;
        float z2 = -0.5f*(LOG2PI + __logf(gv) + sm*glam);
        float zpad = (-1e30f - 0.5f*LOG2PI) * RLN2;
        float4 fA; fA.x = lam2; fA.y = 1.0f; fA.z = glam; fA.w = 0.0f;
        float4 fB; fB.x = (sw + z2)*RLN2; fB.y = zpad; fB.z = 1.0f; fB.w = 1.0f;
        float4 fC; fC.x = 0.0f; fC.y = 0.0f; fC.z = zpad; fC.w = zpad;
        pkc4[0][tid][0] = fA; pkc4[0][tid][1] = fB; pkc4[0][tid][2] = fC;
    } else if (tid < NPAD) {
        // poisoned pad rows 46,47 — written ONCE into BOTH buffers, never
        // rewritten (phase C only writes rows < 46). lam=1/glam=0 keep the
        // key math finite; z=PADZ makes the key ~-1e37 < any real key.
        float4 fA; fA.x = 1.0f; fA.y = 1.0f; fA.z = 0.0f; fA.w = 0.0f;
        float4 fB; fB.x = PADZ; fB.y = PADZ; fB.z = 1.0f; fB.w = 1.0f;
        float4 fC; fC.x = 0.0f; fC.y = 0.0f; fC.z = PADZ; fC.w = PADZ;
        pkc4[0][tid][0] = fA; pkc4[0][tid][1] = fB; pkc4[0][tid][2] = fC;
        pkc4[1][tid][0] = fA; pkc4[1][tid][1] = fB; pkc4[1][tid][2] = fC;
    }
    // ---- emission prefetch for t=1 (dedicated wave 12) ----
    if (tid >= EMB) {
        int pe = tid - EMB;
        if (pe < NLAB) {
            int tok = tokens[b*LSEQ + 1];
            float sw  = s_w_tab[tok*NLAB + pe];
            float sm  = s_m_tab[tok*NLAB + pe];
            float svr = s_v_tab[tok*NLAB + pe];
            float sv = svr*svr;
            float rs = 1.0f / sv;
            float eb = sm * rs;
            float ez = -0.5f*(LOG2PI + __logf(sv) + sm*eb);
            emi[1][pe] = make_float4(sw, rs, eb, ez);
        }
    }
    __syncthreads();

    // ================= the scan: 1 barrier per step =================
    auto stepf = [&](auto CC, int t) {
        constexpr int CUR = decltype(CC)::value;
        if (isA) {
            // ---- upfront carry loads: 9 x ds_read_b128, pinned before compute ----
            float4 ld[3][3];
#pragma unroll
            for (int ci = 0; ci < 3; ++ci) {
                const float4* rp = &pkc4[CUR][s + 16*ci][0];
#pragma unroll
                for (int m = 0; m < 3; ++m) ld[ci][m] = rp[m];
            }
            __builtin_amdgcn_sched_barrier(0);
            float t0=NEGINF, t1=NEGINF, t2=NEGINF, t3=NEGINF;
#define INS(kf, id) {                                                         \
            unsigned kb = (__float_as_uint(kf) & 0xFFFFFF00u) | (unsigned)(id); \
            float fk = __uint_as_float(kb);                                   \
            float n0 = fmaxf(t0, fk);                                         \
            float n1 = fmed3(fk, t0, t1);                                     \
            float n2 = fmed3(fk, t1, t2);                                     \
            float n3 = fmed3(fk, t2, t3);                                     \
            t0=n0; t1=n1; t2=n2; t3=n3; }
#define CANDP(ci, pr, LX, LY, GX, GY, ZX, ZY) {                               \
            v2f lamP;  lamP.x  = LX; lamP.y  = LY;                            \
            v2f glamP; glamP.x = GX; glamP.y = GY;                            \
            v2f zP;    zP.x    = ZX; zP.y    = ZY;                            \
            v2f em0 = glamP + rce0[ci];                                       \
            v2f dm  = lamP * rl11[ci] + rinv[ci];                             \
            v2f tA  = em0 * rl11s[ci] - rqbs[ci];                             \
            v2f tB  = lamP * rqes[ci] + rqcs[ci];                             \
            v2f Q   = em0 * tA + tB;                                          \
            v2f rdm; rdm.x = fastrcp(dm.x); rdm.y = fastrcp(dm.y);            \
            v2f lg;  lg.x  = flog2(dm.x);   lg.y  = flog2(dm.y);              \
            v2f base  = zP + rAs[ci];                                         \
            v2f inner = Q * rdm - lg;                                         \
            v2f keyP  = 0.5f * inner + base;                                  \
            INS(keyP.x, (2*(pr))*NLAB   + s + 16*(ci))                        \
            INS(keyP.y, (2*(pr)+1)*NLAB + s + 16*(ci)) }
            CANDP(0, 0, ld[0][0].x, ld[0][0].y, ld[0][0].z, ld[0][0].w, ld[0][1].x, ld[0][1].y)
            CANDP(0, 1, ld[0][1].z, ld[0][1].w, ld[0][2].x, ld[0][2].y, ld[0][2].z, ld[0][2].w)
            CANDP(1, 0, ld[1][0].x, ld[1][0].y, ld[1][0].z, ld[1][0].w, ld[1][1].x, ld[1][1].y)
            CANDP(1, 1, ld[1][1].z, ld[1][1].w, ld[1][2].x, ld[1][2].y, ld[1][2].z, ld[1][2].w)
            CANDP(2, 0, ld[2][0].x, ld[2][0].y, ld[2][0].z, ld[2][0].w, ld[2][1].x, ld[2][1].y)
            CANDP(2, 1, ld[2][1].z, ld[2][1].w, ld[2][2].x, ld[2][2].y, ld[2][2].z, ld[2][2].w)
#undef CANDP
#undef INS
            // ---- merge across 16-lane group: DPP (m=1,2) + swizzle (m=4) + DPP ror8 ----
#define MSTAGE(F) { float b0=F(t0), b1=F(t1), b2=F(t2), b3=F(t3);                 \
                float M0=fmaxf(t0,b3), M1=fmaxf(t1,b2), M2=fmaxf(t2,b1), M3=fmaxf(t3,b0); \
                float x;                                                          \
                x=fmaxf(M0,M2); M2=fminf(M0,M2); M0=x;  x=fmaxf(M1,M3); M3=fminf(M1,M3); M1=x; \
                x=fmaxf(M0,M1); M1=fminf(M0,M1); M0=x;  x=fmaxf(M2,M3); M3=fminf(M2,M3); M2=x; \
                t0=M0; t1=M1; t2=M2; t3=M3; }
            MSTAGE(dppq<0xB1>)      // xor 1 (quad_perm)
            MSTAGE(dppq<0x4E>)      // xor 2 (quad_perm)
            MSTAGE(swz<0x101F>)     // xor 4 (ds_swizzle)
            {   // final stage xor 8: DPP row_ror:8 (rotate by 8 in 16 == lane^8), set-only
                float b0=dppq<0x128>(t0), b1=dppq<0x128>(t1),
                      b2=dppq<0x128>(t2), b3=dppq<0x128>(t3);
                float M0=fmaxf(t0,b3), M1=fmaxf(t1,b2), M2=fmaxf(t2,b1), M3=fmaxf(t3,b0);
                t0=M0; t1=M1; t2=M2; t3=M3;
            }
#undef MSTAGE
            // ---- phase C: lanes s<4 recompute survivor s exactly + emission ----
            if (s < 4) {
                float sel = (s==0)?t0 : (s==1)?t1 : (s==2)?t2 : t3;
                unsigned kc = __float_as_uint(sel) & 0xFFu;
                unsigned k  = (kc * 1428u) >> 16;
                int c  = (int)kc - (int)k*NLAB;
                int cp = c*NLAB + p;
                float4 ta = tabA[cp];                 // e0,e1,inv,l11
                float2 tb = tabB[cp];                 // l01, A
                const float* sp = (const float*)&pkc4[CUR][c][0]
                                  + 6*(int)(k >> 1) + (int)(k & 1);
                float lam2 = sp[0];
                float glam = sp[2];
                float z2s  = sp[4] * LN2;
                float em0 = ta.x + glam;
                float em1 = ta.y;
                float l01 = tb.x;
                float l00 = fmaf(l01, l01, ta.z) * fastrcp(ta.w);  // (inv+l01^2)/l11
                float dm  = fmaf(lam2, ta.w, ta.z);
                float rdm = fastrcp(dm);
                float lm00 = l00 + lam2;
                float Q = fmaf(em0, fmaf(ta.w, em0, -2.0f*l01*em1), lm00*em1*em1);
                float score = fmaf(0.5f, fmaf(Q, rdm, -__logf(dm)), tb.y + z2s);
                float mu2  = rdm*(lm00*em1 - l01*em0);
                float var2 = lm00*rdm;
                float4 ev = emi[CUR ^ 1][p];
                float rv1 = fastrcp(var2);
                float lam = rv1 + ev.y;
                float emm = fmaf(mu2, rv1, ev.z);
                float vm  = fastrcp(lam);
                float z1 = -0.5f*(LOG2PI + __logf(var2) + mu2*mu2*rv1);
                float zm = -0.5f*(LOG2PI + __logf(vm) + emm*emm*vm);
                float nsc = score + (z1 + ev.w - zm) + ev.x;
                float* wp = (float*)&pkc4[CUR ^ 1][p][0] + 6*(s >> 1) + (s & 1);
                wp[0] = lam;
                wp[2] = emm;
                wp[4] = (nsc + zm) * RLN2;
                if (t == LSEQ - 1) scv[s*NLAB + p] = nsc;   // only last step feeds LSE
            }
        } else if (tid >= EMB) {
            // ---- emission prefetch for step t+1 into emi[CUR] (wave 12) ----
            int pe = tid - EMB;
            if (pe < NLAB && t + 1 < LSEQ) {
                int tok = tokL[t + 1];
                float sw  = s_w_tab[tok*NLAB + pe];
                float sm  = s_m_tab[tok*NLAB + pe];
                float svr = s_v_tab[tok*NLAB + pe];
                float sv = svr*svr;
                float rs = 1.0f / sv;
                float eb = sm * rs;
                float ez = -0.5f*(LOG2PI + __logf(sv) + sm*eb);
                emi[CUR][pe] = make_float4(sw, rs, eb, ez);
            }
        }
        __syncthreads();   // the ONLY barrier per step
    };

    int t = 1;
#pragma unroll 1
    for (int it = 0; it < (LSEQ - 2) / 2; ++it) {   // 255 double-steps: t=1..510
        stepf(IC<0>{}, t); ++t;
        stepf(IC<1>{}, t); ++t;
    }
    stepf(IC<0>{}, t);   // t = 511

    // ---- final logsumexp over 184 component scores (wave 0) ----
    if (tid < 64) {
        float mx = -1e38f;
        for (int i = tid; i < KC; i += 64) mx = fmaxf(mx, scv[i]);
#pragma unroll
        for (int m = 32; m; m >>= 1) mx = fmaxf(mx, __shfl_xor(mx, m, 64));
        float sum = 0.0f;
        for (int i = tid; i < KC; i += 64) sum += __expf(scv[i] - mx);
#pragma unroll
        for (int m = 32; m; m >>= 1) sum += __shfl_xor(sum, m, 64);
        if (tid == 0) out[b] = mx + __logf(sum);
    }
}

extern "C" void kernel_launch(void* const* d_in, const int* in_sizes, int n_in,
                              void* d_out, int out_size, void* d_ws, size_t ws_size,
                              hipStream_t stream) {
    const int*   tokens = (const int*)d_in[0];
    const float* sw     = (const float*)d_in[1];
    const float* sm     = (const float*)d_in[2];
    const float* sv     = (const float*)d_in[3];
    const float* tw     = (const float*)d_in[4];
    const float* tmu    = (const float*)d_in[5];
    const float* tvp    = (const float*)d_in[6];
    float* o = (float*)d_out;
    hipLaunchKernelGGL(lveg_kernel, dim3(64), dim3(BLOCK), 0, stream,
                       tokens, sw, sm, sv, tw, tmu, tvp, o);
}

// Round 2
// 1002.109 us; speedup vs baseline: 1.1340x; 1.1099x over previous
//
#include <hip/hip_runtime.h>

#define LOG2PI 1.837877f
#define LN2 0.6931471805599453f
#define RLN2 1.4426950408889634f
#define NLAB 46
#define NPAD 48           // children padded to 48 with poisoned carry rows
#define KK 4
#define LSEQ 512
#define KC 184            // KK*NLAB
#define BLOCK 832         // 13 waves: 12 A-waves + light emission wave 12
#define NA 736            // 46 parents * 16 lanes
#define EMB 768           // emission wave start
#define PADZ -1e37f       // pad-row z: finite, below every real key, no NaN on pack

typedef float v2f __attribute__((ext_vector_type(2)));

__device__ __forceinline__ float fastrcp(float x){ return __builtin_amdgcn_rcpf(x); }
__device__ __forceinline__ float flog2(float x){ return __builtin_amdgcn_logf(x); }
__device__ __forceinline__ float fmed3(float a, float b, float c){
    return __builtin_amdgcn_fmed3f(a, b, c);
}
template<int CTRL>
__device__ __forceinline__ float dppq(float v){   // DPP exchange (VALU pipe)
    return __uint_as_float((unsigned)__builtin_amdgcn_mov_dpp(
        (int)__float_as_uint(v), CTRL, 0xF, 0xF, false));
}
template<int N> struct IC { static constexpr int value = N; };

__global__ __launch_bounds__(BLOCK, 4) void lveg_kernel(
    const int* __restrict__ tokens,
    const float* __restrict__ s_w_tab,
    const float* __restrict__ s_m_tab,
    const float* __restrict__ s_v_tab,
    const float* __restrict__ t_weight,
    const float* __restrict__ t_mu,
    const float* __restrict__ t_var_p,
    float* __restrict__ out)
{
    // carry per child c (row = 48B = 3 float4), dword layout:
    // [lam0,lam1, glam0,glam1, z0,z1, lam2,lam3, glam2,glam3, z2,z3]
    // (z entries stored scaled by RLN2 for the selection key path;
    //  z slot holds (score+z1+ez+sw)*RLN2 — the zm term cancels algebraically)
    __shared__ float4 pkc4[2][NPAD][3];
    __shared__ float  scv[KC];           // raw final scores (nsc) for logsumexp
    __shared__ float4 emi[2][NLAB];      // emission: sw+ez, 1/sv, sm/sv, 0
    __shared__ int    tokL[LSEQ];
    __shared__ float4 tabA[NLAB*NLAB];   // per-(c,p): e0, e1, invDetS, l11
    __shared__ float2 tabB[NLAB*NLAB];   // per-(c,p): l01, A'(=zeta1+0.5*LOG2PI+tw)

    const int b = blockIdx.x;
    const int tid = threadIdx.x;
    const int s = tid & 15;              // lane within 16-lane parent group
    const int p = tid >> 4;              // parent label 0..51
    const bool isA = (p < NLAB);
    const float NEGINF = __uint_as_float(0xFF800000u);

    // ---- one-time: phase-C constant tables into LDS + token preload ----
    for (int cp = tid; cp < NLAB*NLAB; cp += BLOCK) {
        float v0 = t_var_p[cp*3+0], v1 = t_var_p[cp*3+1], v2 = t_var_p[cp*3+2];
        float tm0 = t_mu[cp*2+0],  tm1 = t_mu[cp*2+1];
        float S00 = v0*v0 + v1*v1, S01 = v1*v2, S11 = v2*v2;
        float det = S00*S11 - S01*S01;
        float inv = 1.0f / det;
        float l00 = S11*inv, l01 = -S01*inv, l11 = S00*inv;
        float e0 = l00*tm0 + l01*tm1;
        float e1 = l01*tm0 + l11*tm1;
        float q1 = e0*(S00*e0 + S01*e1) + e1*(S01*e0 + S11*e1);
        float zeta1 = -0.5f*(2.0f*LOG2PI + __logf(det) + q1);
        tabA[cp] = make_float4(e0, e1, inv, l11);
        tabB[cp] = make_float2(l01, zeta1 + 0.5f*LOG2PI + t_weight[cp]);
    }
    for (int i = tid; i < LSEQ; i += BLOCK) tokL[i] = tokens[b*LSEQ + i];

    // ---- one-time: phase-A per-(c,p) constants in registers ----
    float rce0[3], rl11[3], rinv[3], rl11s[3], rqbs[3], rqes[3], rqcs[3], rAs[3];
    if (isA) {
#pragma unroll
        for (int ci = 0; ci < 3; ++ci) {
            int c = s + 16*ci;
            if (c < NLAB) {
                int cp = c*NLAB + p;
                float v0 = t_var_p[cp*3+0], v1 = t_var_p[cp*3+1], v2 = t_var_p[cp*3+2];
                float tm0 = t_mu[cp*2+0],  tm1 = t_mu[cp*2+1];
                float S00 = v0*v0 + v1*v1, S01 = v1*v2, S11 = v2*v2;
                float det = S00*S11 - S01*S01;
                float inv = 1.0f / det;
                float l00 = S11*inv, l01 = -S01*inv, l11 = S00*inv;
                float e0 = l00*tm0 + l01*tm1;
                float e1 = l01*tm0 + l11*tm1;
                float q1 = e0*(S00*e0 + S01*e1) + e1*(S01*e0 + S11*e1);
                float zeta1 = -0.5f*(2.0f*LOG2PI + __logf(det) + q1);
                rce0[ci]  = e0;
                rl11[ci]  = l11;
                rinv[ci]  = inv;
                rl11s[ci] = l11 * RLN2;
                rqbs[ci]  = 2.0f*l01*e1 * RLN2;
                rqes[ci]  = e1*e1 * RLN2;
                rqcs[ci]  = l00*e1*e1 * RLN2;
                rAs[ci]   = (zeta1 + LOG2PI + t_weight[cp]) * RLN2;
            } else {
                // pad children 46,47: finite math, key dominated by z=PADZ
                rce0[ci]=0.f; rl11[ci]=0.f; rinv[ci]=1.f; rl11s[ci]=0.f;
                rqbs[ci]=0.f; rqes[ci]=0.f; rqcs[ci]=0.f; rAs[ci]=0.f;
            }
        }
    }

    // ---- carry init from emission at position 0 ----
    if (tid < NLAB) {
        int tok0 = tokens[b * LSEQ];
        float sw  = s_w_tab[tok0*NLAB + tid];
        float sm  = s_m_tab[tok0*NLAB + tid];
        float svr = s_v_tab[tok0*NLAB + tid];
        float gv = svr*svr;
        float lam2 = 1.0f / gv;
        float glam = sm * lam2;
        float z2 = -0.5f*(LOG2PI + __logf(gv) + sm*glam);
        float zpad = (-1e30f - 0.5f*LOG2PI) * RLN2;
        float4 fA; fA.x = lam2; fA.y = 1.0f; fA.z = glam; fA.w = 0.0f;
        float4 fB; fB.x = (sw + z2)*RLN2; fB.y = zpad; fB.z = 1.0f; fB.w = 1.0f;
        float4 fC; fC.x = 0.0f; fC.y = 0.0f; fC.z = zpad; fC.w = zpad;
        pkc4[0][tid][0] = fA; pkc4[0][tid][1] = fB; pkc4[0][tid][2] = fC;
    } else if (tid < NPAD) {
        // poisoned pad rows 46,47 — written ONCE into BOTH buffers, never
        // rewritten (phase C only writes rows < 46). lam=1/glam=0 keep the
        // key math finite; z=PADZ makes the key ~-1e37 < any real key.
        float4 fA; fA.x = 1.0f; fA.y = 1.0f; fA.z = 0.0f; fA.w = 0.0f;
        float4 fB; fB.x = PADZ; fB.y = PADZ; fB.z = 1.0f; fB.w = 1.0f;
        float4 fC; fC.x = 0.0f; fC.y = 0.0f; fC.z = PADZ; fC.w = PADZ;
        pkc4[0][tid][0] = fA; pkc4[0][tid][1] = fB; pkc4[0][tid][2] = fC;
        pkc4[1][tid][0] = fA; pkc4[1][tid][1] = fB; pkc4[1][tid][2] = fC;
    }
    // ---- emission prefetch for t=1 (dedicated wave 12) ----
    if (tid >= EMB) {
        int pe = tid - EMB;
        if (pe < NLAB) {
            int tok = tokens[b*LSEQ + 1];
            float sw  = s_w_tab[tok*NLAB + pe];
            float sm  = s_m_tab[tok*NLAB + pe];
            float svr = s_v_tab[tok*NLAB + pe];
            float sv = svr*svr;
            float rs = 1.0f / sv;
            float eb = sm * rs;
            float ez = -0.5f*(LOG2PI + __logf(sv) + sm*eb);
            emi[1][pe] = make_float4(sw + ez, rs, eb, 0.0f);
        }
    }
    __syncthreads();

    // ================= the scan: 1 barrier per step =================
    auto stepf = [&](auto CC, auto FF, int t) {
        constexpr int CUR = decltype(CC)::value;
        constexpr bool FIN = (decltype(FF)::value != 0);
        if (isA) {
            // ---- upfront carry loads: 9 x ds_read_b128, pinned before compute ----
            float4 ld[3][3];
#pragma unroll
            for (int ci = 0; ci < 3; ++ci) {
                const float4* rp = &pkc4[CUR][s + 16*ci][0];
#pragma unroll
                for (int m = 0; m < 3; ++m) ld[ci][m] = rp[m];
            }
            __builtin_amdgcn_sched_barrier(0);
            float t0=NEGINF, t1=NEGINF, t2=NEGINF, t3=NEGINF;
#define INS(kf, id) {                                                         \
            unsigned kb = (__float_as_uint(kf) & 0xFFFFFF00u) | (unsigned)(id); \
            float fk = __uint_as_float(kb);                                   \
            float n0 = fmaxf(t0, fk);                                         \
            float n1 = fmed3(fk, t0, t1);                                     \
            float n2 = fmed3(fk, t1, t2);                                     \
            float n3 = fmed3(fk, t2, t3);                                     \
            t0=n0; t1=n1; t2=n2; t3=n3; }
#define CANDP(ci, pr, LX, LY, GX, GY, ZX, ZY) {                               \
            v2f lamP;  lamP.x  = LX; lamP.y  = LY;                            \
            v2f glamP; glamP.x = GX; glamP.y = GY;                            \
            v2f zP;    zP.x    = ZX; zP.y    = ZY;                            \
            v2f em0 = glamP + rce0[ci];                                       \
            v2f dm  = lamP * rl11[ci] + rinv[ci];                             \
            v2f tA  = em0 * rl11s[ci] - rqbs[ci];                             \
            v2f tB  = lamP * rqes[ci] + rqcs[ci];                             \
            v2f Q   = em0 * tA + tB;                                          \
            v2f rdm; rdm.x = fastrcp(dm.x); rdm.y = fastrcp(dm.y);            \
            v2f lg;  lg.x  = flog2(dm.x);   lg.y  = flog2(dm.y);              \
            v2f base  = zP + rAs[ci];                                         \
            v2f inner = Q * rdm - lg;                                         \
            v2f keyP  = 0.5f * inner + base;                                  \
            INS(keyP.x, (2*(pr))*NLAB   + s + 16*(ci))                        \
            INS(keyP.y, (2*(pr)+1)*NLAB + s + 16*(ci)) }
            CANDP(0, 0, ld[0][0].x, ld[0][0].y, ld[0][0].z, ld[0][0].w, ld[0][1].x, ld[0][1].y)
            CANDP(0, 1, ld[0][1].z, ld[0][1].w, ld[0][2].x, ld[0][2].y, ld[0][2].z, ld[0][2].w)
            CANDP(1, 0, ld[1][0].x, ld[1][0].y, ld[1][0].z, ld[1][0].w, ld[1][1].x, ld[1][1].y)
            CANDP(1, 1, ld[1][1].z, ld[1][1].w, ld[1][2].x, ld[1][2].y, ld[1][2].z, ld[1][2].w)
            CANDP(2, 0, ld[2][0].x, ld[2][0].y, ld[2][0].z, ld[2][0].w, ld[2][1].x, ld[2][1].y)
            CANDP(2, 1, ld[2][1].z, ld[2][1].w, ld[2][2].x, ld[2][2].y, ld[2][2].z, ld[2][2].w)
#undef CANDP
#undef INS
            // ---- merge across 16-lane group: ALL-DPP (VALU pipe only) ----
            // After stages xor1+xor2 each 4-group holds an identical sorted
            // list, so stage 3 only needs ANY pairing that crosses the two
            // 4-groups inside an 8-group: ROW_HALF_MIRROR (l -> 7-l). Same
            // argument lets stage 4 use row_ror:8.
#define MSTAGE(F) { float b0=F(t0), b1=F(t1), b2=F(t2), b3=F(t3);                 \
                float M0=fmaxf(t0,b3), M1=fmaxf(t1,b2), M2=fmaxf(t2,b1), M3=fmaxf(t3,b0); \
                float x;                                                          \
                x=fmaxf(M0,M2); M2=fminf(M0,M2); M0=x;  x=fmaxf(M1,M3); M3=fminf(M1,M3); M1=x; \
                x=fmaxf(M0,M1); M1=fminf(M0,M1); M0=x;  x=fmaxf(M2,M3); M3=fminf(M2,M3); M2=x; \
                t0=M0; t1=M1; t2=M2; t3=M3; }
            MSTAGE(dppq<0xB1>)      // xor 1 (quad_perm)
            MSTAGE(dppq<0x4E>)      // xor 2 (quad_perm)
            MSTAGE(dppq<0x141>)     // cross-4 pairing (ROW_HALF_MIRROR)
            {   // final stage: cross-8 pairing (row_ror:8), set-only
                float b0=dppq<0x128>(t0), b1=dppq<0x128>(t1),
                      b2=dppq<0x128>(t2), b3=dppq<0x128>(t3);
                float M0=fmaxf(t0,b3), M1=fmaxf(t1,b2), M2=fmaxf(t2,b1), M3=fmaxf(t3,b0);
                t0=M0; t1=M1; t2=M2; t3=M3;
            }
#undef MSTAGE
            // ---- phase C: lanes s<4 recompute survivor s exactly + emission ----
            // ln(var2) = ln(lm00) - ln(dm) makes the ln(dm) in score+z1 cancel;
            // the stored z-carry is (score+z1+ez+sw)*RLN2 (zm cancels), so the
            // whole vm/zm/nsc block is FIN-only.
            if (s < 4) {
                float sel = (s==0)?t0 : (s==1)?t1 : (s==2)?t2 : t3;
                unsigned kc = __float_as_uint(sel) & 0xFFu;
                unsigned k  = (kc * 1428u) >> 16;
                int c  = (int)kc - (int)k*NLAB;
                int cp = c*NLAB + p;
                float4 ta = tabA[cp];                 // e0,e1,inv,l11
                float2 tb = tabB[cp];                 // l01, A' = zeta1+0.5*LOG2PI+tw
                const float* sp = (const float*)&pkc4[CUR][c][0]
                                  + 6*(int)(k >> 1) + (int)(k & 1);
                float lam2 = sp[0];
                float glam = sp[2];
                float z2s  = sp[4] * LN2;
                float em0 = ta.x + glam;
                float em1 = ta.y;
                float l01 = tb.x;
                float dm  = fmaf(lam2, ta.w, ta.z);
                float rdm = fastrcp(dm);
                float lm00 = fmaf(l01, l01, dm) * fastrcp(ta.w);  // l00 + lam2
                float Q = fmaf(em0, fmaf(ta.w, em0, -2.0f*l01*em1), lm00*em1*em1);
                float mu2  = rdm*(lm00*em1 - l01*em0);
                float rlm  = fastrcp(lm00);
                float rv1  = dm * rlm;                // 1/var2
                float lnlm = __logf(lm00);
                float4 ev = emi[CUR ^ 1][p];          // (sw+ez, 1/sv, sm/sv, 0)
                float lam = rv1 + ev.y;
                float emm = fmaf(mu2, rv1, ev.z);
                float sz  = fmaf(0.5f, fmaf(Q, rdm, -fmaf(mu2*mu2, rv1, lnlm)),
                                 tb.y + z2s + ev.x);
                float* wp = (float*)&pkc4[CUR ^ 1][p][0] + 6*(s >> 1) + (s & 1);
                wp[0] = lam;
                wp[2] = emm;
                wp[4] = sz * RLN2;
                if (FIN) {
                    float vm = fastrcp(lam);
                    float zm = -0.5f*(LOG2PI + __logf(vm) + emm*emm*vm);
                    scv[s*NLAB + p] = sz - zm;        // nsc, feeds logsumexp
                }
            }
        } else if (tid >= EMB) {
            // ---- emission prefetch for step t+1 into emi[CUR] (wave 12) ----
            int pe = tid - EMB;
            if (pe < NLAB && t + 1 < LSEQ) {
                int tok = tokL[t + 1];
                float sw  = s_w_tab[tok*NLAB + pe];
                float sm  = s_m_tab[tok*NLAB + pe];
                float svr = s_v_tab[tok*NLAB + pe];
                float sv = svr*svr;
                float rs = 1.0f / sv;
                float eb = sm * rs;
                float ez = -0.5f*(LOG2PI + __logf(sv) + sm*eb);
                emi[CUR][pe] = make_float4(sw + ez, rs, eb, 0.0f);
            }
        }
        __syncthreads();   // the ONLY barrier per step
    };

    int t = 1;
#pragma unroll 1
    for (int it = 0; it < (LSEQ - 2) / 2; ++it) {   // 255 double-steps: t=1..510
        stepf(IC<0>{}, IC<0>{}, t); ++t;
        stepf(IC<1>{}, IC<0>{}, t); ++t;
    }
    stepf(IC<0>{}, IC<1>{}, t);   // t = 511 (FIN: computes zm/nsc -> scv)

    // ---- final logsumexp over 184 component scores (wave 0) ----
    if (tid < 64) {
        float mx = -1e38f;
        for (int i = tid; i < KC; i += 64) mx = fmaxf(mx, scv[i]);
#pragma unroll
        for (int m = 32; m; m >>= 1) mx = fmaxf(mx, __shfl_xor(mx, m, 64));
        float sum = 0.0f;
        for (int i = tid; i < KC; i += 64) sum += __expf(scv[i] - mx);
#pragma unroll
        for (int m = 32; m; m >>= 1) sum += __shfl_xor(sum, m, 64);
        if (tid == 0) out[b] = mx + __logf(sum);
    }
}

extern "C" void kernel_launch(void* const* d_in, const int* in_sizes, int n_in,
                              void* d_out, int out_size, void* d_ws, size_t ws_size,
                              hipStream_t stream) {
    const int*   tokens = (const int*)d_in[0];
    const float* sw     = (const float*)d_in[1];
    const float* sm     = (const float*)d_in[2];
    const float* sv     = (const float*)d_in[3];
    const float* tw     = (const float*)d_in[4];
    const float* tmu    = (const float*)d_in[5];
    const float* tvp    = (const float*)d_in[6];
    float* o = (float*)d_out;
    hipLaunchKernelGGL(lveg_kernel, dim3(64), dim3(BLOCK), 0, stream,
                       tokens, sw, sm, sv, tw, tmu, tvp, o);
}